// Round 1
// baseline (235.616 us; speedup 1.0000x reference)
//
#include <hip/hip_runtime.h>
#include <hip/hip_bf16.h>

// Head attention, B=8, T=4096, C=512, h=64, prefix-causal mask (j <= max(i,1023)).
// Inputs/output fp32; internal q/Kf/Vf bf16 in ws. Round-7: attn gets a
// register double-buffered K/V prefetch (one kt-iteration ahead) to hide
// L2/L3 load latency at 2 waves/SIMD; softmax scale folded into q at proj
// time (saves 64 v_mul per kt-iter); proj front-loads all 16 x-loads per
// wave for max MLP. Structure otherwise identical to round-6.

typedef short short8 __attribute__((ext_vector_type(8)));   // 8 bf16 = 4 VGPRs
typedef float floatx4 __attribute__((ext_vector_type(4)));

// fp32 -> bf16 RNE (scalar)
static __device__ __forceinline__ unsigned short f2b(float f) {
  unsigned u = __float_as_uint(f);
  unsigned r = (u + 0x7fffu + ((u >> 16) & 1u)) >> 16;
  return (unsigned short)r;
}

// pack 2 fp32 -> bf16x2 dword (RNE packed convert)
static __device__ __forceinline__ unsigned pkbf(float lo, float hi) {
  __hip_bfloat162 t = __float22bfloat162_rn(make_float2(lo, hi));
  unsigned d;
  __builtin_memcpy(&d, &t, 4);
  return d;
}

union S8U {
  short8 s;
  unsigned u[4];
};

// ---------------------------------------------------------------------------
// Kernel 0: weights -> frag-linear Wtf[(ks*12 + j)*512 + lane*8 + e] bf16.
__global__ __launch_bounds__(256) void wtrans(
    const float* __restrict__ Wq, const float* __restrict__ Wk,
    const float* __restrict__ Wv, unsigned short* __restrict__ Wtf) {
  int o = blockIdx.x * 256 + threadIdx.x;  // 0..98303
  int e = o & 7;
  int ln = (o >> 3) & 63;
  int jg = o >> 9;          // ks*12 + j, 0..191
  int ks = jg / 12;
  int j = jg % 12;
  int m = j >> 2;
  int n = (j & 3) * 16 + (ln & 15);
  int k = ks * 32 + (ln >> 4) * 8 + e;
  const float* W = (m == 0) ? Wq : (m == 1) ? Wk : Wv;
  Wtf[o] = f2b(W[k * 64 + n]);
}

// ---------------------------------------------------------------------------
// Kernel 1: 1024 blocks x 32 rows. Barrier-free 2-way-K-split GEMM; all 16
// per-wave x loads issued up front (64 VGPR) so HBM requests overlap the
// whole MFMA chain. q stored pre-scaled by C^-0.5 * log2e.
__global__ __launch_bounds__(256, 3) void proj(
    const float* __restrict__ x, const unsigned short* __restrict__ Wtf,
    unsigned short* __restrict__ q, unsigned short* __restrict__ Kf,
    unsigned short* __restrict__ Vf) {
  __shared__ float Cc[2][12][16][17];  // partial-acc exchange, padded

  const int tid = threadIdx.x;
  const int lane = tid & 63;
  const int w = tid >> 6;
  const int u = lane & 15;
  const int qd = lane >> 4;
  const int pr = w >> 1;   // row-pair: rows g0 + pr*16 .. +15
  const int p = w & 1;     // ks parity
  const int g0 = blockIdx.x * 32;

  const float* xr = x + (size_t)(g0 + pr * 16 + u) * 512;

  // front-load all x reads for this wave (16 x 16B = 64 VGPRs)
  floatx4 xv[16];
#pragma unroll
  for (int it = 0; it < 8; ++it) {
    const int ks = p + it * 2;
    xv[it * 2] = *reinterpret_cast<const floatx4*>(&xr[ks * 32 + qd * 8]);
    xv[it * 2 + 1] = *reinterpret_cast<const floatx4*>(&xr[ks * 32 + qd * 8 + 4]);
  }

  floatx4 acc[12];
#pragma unroll
  for (int j = 0; j < 12; ++j) acc[j] = (floatx4)0.0f;

#pragma unroll
  for (int it = 0; it < 8; ++it) {
    const int ks = p + it * 2;
    S8U a;
    a.u[0] = pkbf(xv[it * 2][0], xv[it * 2][1]);
    a.u[1] = pkbf(xv[it * 2][2], xv[it * 2][3]);
    a.u[2] = pkbf(xv[it * 2 + 1][0], xv[it * 2 + 1][1]);
    a.u[3] = pkbf(xv[it * 2 + 1][2], xv[it * 2 + 1][3]);
#pragma unroll
    for (int j = 0; j < 12; ++j) {
      short8 bfr = *reinterpret_cast<const short8*>(&Wtf[(size_t)(ks * 12 + j) * 512 + lane * 8]);
      acc[j] = __builtin_amdgcn_mfma_f32_16x16x32_bf16(a.s, bfr, acc[j], 0, 0, 0);
    }
  }

  // combine parities: p==1 publishes, p==0 adds
  if (p == 1) {
#pragma unroll
    for (int j = 0; j < 12; ++j)
#pragma unroll
      for (int r = 0; r < 4; ++r)
        Cc[pr][j][qd * 4 + r][u] = acc[j][r];
  }
  __syncthreads();
  if (p == 0) {
#pragma unroll
    for (int j = 0; j < 12; ++j)
#pragma unroll
      for (int r = 0; r < 4; ++r)
        acc[j][r] += Cc[pr][j][qd * 4 + r][u];

    // ---- epilogue (2 active waves, 16 rows each) ----
    const float cexp = 0.04419417382415922f * 1.4426950408889634f;  // C^-0.5*log2e
    const int rbase = g0 + pr * 16;
    const int b = rbase >> 12;
    const int t = rbase & 4095;
    const int kt = t >> 6;
    const int sb = ((blockIdx.x & 1) << 1) + pr;      // K frag row-block in tile
    const int sp = blockIdx.x & 1;                     // V frag s-half in tile
    unsigned short* kfb = Kf + ((size_t)(b * 64 + kt)) * 4096;
    unsigned short* vfb = Vf + ((size_t)(b * 64 + kt)) * 4096;

#pragma unroll
    for (int j = 0; j < 4; ++j)
#pragma unroll
      for (int r = 0; r < 4; ++r) {
        // q row-major, pre-scaled so attn's exp2 needs no multiply
        q[(size_t)(rbase + qd * 4 + r) * 64 + j * 16 + u] = f2b(acc[j][r] * cexp);
        // Kf: frag f = kh*4+sb; lane (qd_f, u_f=qd*4+r), elem e=u&7
        {
          int kh = j >> 1;
          int qd_f = ((j & 1) << 1) + (u >> 3);
          kfb[(size_t)(kh * 4 + sb) * 512 + (qd_f * 16 + (qd * 4 + r)) * 8 + (u & 7)] =
              f2b(acc[4 + j][r]);
        }
        // Vf: frag f = sp*4+mb (mb=j); lane (qd_f, u_f=u), elem e
        {
          int qd_f = pr * 2 + (qd >> 1);
          int e = ((qd & 1) << 2) + r;
          vfb[(size_t)(sp * 4 + j) * 512 + (qd_f * 16 + u) * 8 + e] = f2b(acc[8 + j][r]);
        }
      }
  }
}

// ---------------------------------------------------------------------------
// Kernel 2: flash attention, transposed-S, register double-buffered K/V
// prefetch (one kt-iteration ahead). 512 blocks (b = bx&7 -> XCD, qt paired
// heavy/light). 4 waves each own ALL 64 q-rows for kt = w, w+4, ...
__global__ __launch_bounds__(256, 2) void attn(
    const unsigned short* __restrict__ q, const unsigned short* __restrict__ Kf,
    const unsigned short* __restrict__ Vf, float* __restrict__ out) {
  __shared__ unsigned Pb[4][4][64][4];   // [wave][nb][lane][dword] 16 KB
  __shared__ float OcA[64][68];          // combine buffers [qr][h], padded
  __shared__ float OcB[64][68];
  __shared__ float Lc[4][64];

  const int tid = threadIdx.x;
  const int lane = tid & 63;
  const int w = tid >> 6;
  const int u = lane & 15;
  const int qd = lane >> 4;

  const int bx = blockIdx.x;
  const int b = bx & 7;
  const int i = bx >> 3;
  const int qt = (i < 32) ? i : (95 - i);
  const int g0 = qt * 64;

  const unsigned short* qp = q + (size_t)b * 4096 * 64;
  const unsigned short* kfp = Kf + (size_t)b * 64 * 4096;
  const unsigned short* vfp = Vf + (size_t)b * 64 * 4096;

  // Q B-frags (all 64 rows): qB[nb][kh]
  short8 qB[4][2];
#pragma unroll
  for (int nb = 0; nb < 4; ++nb)
#pragma unroll
    for (int kh = 0; kh < 2; ++kh)
      qB[nb][kh] = *reinterpret_cast<const short8*>(
          &qp[(size_t)(g0 + nb * 16 + u) * 64 + kh * 32 + qd * 8]);

  floatx4 OT[4][4];  // [mb][nb]: O^T[h=mb*16+qd*4+r][qr=nb*16+u]
#pragma unroll
  for (int mb = 0; mb < 4; ++mb)
#pragma unroll
    for (int nb = 0; nb < 4; ++nb) OT[mb][nb] = (floatx4)0.0f;
  float L[4] = {0.f, 0.f, 0.f, 0.f};

  const int ktmax = (qt < 16) ? 15 : qt;

// load K/V frags for tile KT into named register buffers
#define LOADKV(KA, VA, KT)                                                    \
  do {                                                                        \
    const unsigned short* kb_ = kfp + (size_t)(KT) * 4096;                    \
    const unsigned short* vb_ = vfp + (size_t)(KT) * 4096;                    \
    _Pragma("unroll")                                                         \
    for (int f = 0; f < 8; ++f) {                                             \
      KA[f] = *reinterpret_cast<const short8*>(&kb_[(size_t)f * 512 + lane * 8]); \
      VA[f] = *reinterpret_cast<const short8*>(&vb_[(size_t)f * 512 + lane * 8]); \
    }                                                                         \
  } while (0)

// full S^T -> exp -> pack -> PV step for one kt tile (q pre-scaled in proj)
#define ATTN_STEP(KA, VA, KT)                                                 \
  do {                                                                        \
    const bool diag_ = (qt >= 16) && ((KT) == qt);                            \
    _Pragma("unroll")                                                         \
    for (int sp = 0; sp < 2; ++sp) {                                          \
      floatx4 ST[2][4];                                                       \
      _Pragma("unroll")                                                       \
      for (int sbb = 0; sbb < 2; ++sbb)                                       \
        _Pragma("unroll")                                                     \
        for (int nb = 0; nb < 4; ++nb) ST[sbb][nb] = (floatx4)0.0f;           \
      _Pragma("unroll")                                                       \
      for (int kh = 0; kh < 2; ++kh)                                          \
        _Pragma("unroll")                                                     \
        for (int sbb = 0; sbb < 2; ++sbb)                                     \
          _Pragma("unroll")                                                   \
          for (int nb = 0; nb < 4; ++nb)                                      \
            ST[sbb][nb] = __builtin_amdgcn_mfma_f32_16x16x32_bf16(            \
                KA[kh * 4 + sp * 2 + sbb], qB[nb][kh], ST[sbb][nb], 0, 0, 0); \
      if (diag_) {                                                            \
        _Pragma("unroll")                                                     \
        for (int sbb = 0; sbb < 2; ++sbb)                                     \
          _Pragma("unroll")                                                   \
          for (int nb = 0; nb < 4; ++nb)                                      \
            _Pragma("unroll")                                                 \
            for (int r = 0; r < 4; ++r) {                                     \
              int sl = (sp * 2 + sbb) * 16 + qd * 4 + r;                      \
              int qr = nb * 16 + u;                                           \
              if (sl > qr) ST[sbb][nb][r] = -__builtin_inff();                \
            }                                                                 \
      }                                                                       \
      _Pragma("unroll")                                                       \
      for (int sbb = 0; sbb < 2; ++sbb)                                       \
        _Pragma("unroll")                                                     \
        for (int nb = 0; nb < 4; ++nb) {                                      \
          _Pragma("unroll")                                                   \
          for (int r = 0; r < 4; ++r)                                         \
            ST[sbb][nb][r] = __builtin_amdgcn_exp2f(ST[sbb][nb][r]);          \
          L[nb] += (ST[sbb][nb][0] + ST[sbb][nb][1]) +                        \
                   (ST[sbb][nb][2] + ST[sbb][nb][3]);                         \
          unsigned lo = pkbf(ST[sbb][nb][0], ST[sbb][nb][1]);                 \
          unsigned hi = pkbf(ST[sbb][nb][2], ST[sbb][nb][3]);                 \
          int dl = (sbb * 2 + (qd >> 1)) * 16 + u;                            \
          int d0 = (qd & 1) * 2;                                              \
          *reinterpret_cast<uint2*>(&Pb[w][nb][dl][d0]) = make_uint2(lo, hi); \
        }                                                                     \
      _Pragma("unroll")                                                       \
      for (int nb = 0; nb < 4; ++nb) {                                        \
        short8 pB = *reinterpret_cast<const short8*>(&Pb[w][nb][lane][0]);    \
        _Pragma("unroll")                                                     \
        for (int mb = 0; mb < 4; ++mb)                                        \
          OT[mb][nb] = __builtin_amdgcn_mfma_f32_16x16x32_bf16(               \
              VA[sp * 4 + mb], pB, OT[mb][nb], 0, 0, 0);                      \
      }                                                                       \
    }                                                                         \
  } while (0)

  // software pipeline: named double buffers (static indexing only)
  short8 kAa[8], vAa[8], kAb[8], vAb[8];
  LOADKV(kAa, vAa, w);
  int kt = w;
  for (;;) {
    int ktn = kt + 4;
    if (ktn <= ktmax) {
      LOADKV(kAb, vAb, ktn);
      ATTN_STEP(kAa, vAa, kt);
    } else {
      ATTN_STEP(kAa, vAa, kt);
      break;
    }
    kt = ktn;
    ktn = kt + 4;
    if (ktn <= ktmax) {
      LOADKV(kAa, vAa, ktn);
      ATTN_STEP(kAb, vAb, kt);
    } else {
      ATTN_STEP(kAb, vAb, kt);
      break;
    }
    kt = ktn;
  }

#undef LOADKV
#undef ATTN_STEP

  // ---- combine across the 4 kt-split waves ----
#pragma unroll
  for (int nb = 0; nb < 4; ++nb) {
    L[nb] += __shfl_xor(L[nb], 16);
    L[nb] += __shfl_xor(L[nb], 32);
  }
  if (lane < 16) {
#pragma unroll
    for (int nb = 0; nb < 4; ++nb) Lc[w][nb * 16 + lane] = L[nb];
  }

  if (w == 1) {
#pragma unroll
    for (int mb = 0; mb < 4; ++mb)
#pragma unroll
      for (int nb = 0; nb < 4; ++nb)
        *reinterpret_cast<floatx4*>(&OcA[nb * 16 + u][mb * 16 + qd * 4]) = OT[mb][nb];
  }
  if (w == 3) {
#pragma unroll
    for (int mb = 0; mb < 4; ++mb)
#pragma unroll
      for (int nb = 0; nb < 4; ++nb)
        *reinterpret_cast<floatx4*>(&OcB[nb * 16 + u][mb * 16 + qd * 4]) = OT[mb][nb];
  }
  __syncthreads();
  if (w == 0) {
#pragma unroll
    for (int mb = 0; mb < 4; ++mb)
#pragma unroll
      for (int nb = 0; nb < 4; ++nb)
        OT[mb][nb] += *reinterpret_cast<const floatx4*>(&OcA[nb * 16 + u][mb * 16 + qd * 4]);
  }
  if (w == 2) {
#pragma unroll
    for (int mb = 0; mb < 4; ++mb)
#pragma unroll
      for (int nb = 0; nb < 4; ++nb) {
        OT[mb][nb] += *reinterpret_cast<const floatx4*>(&OcB[nb * 16 + u][mb * 16 + qd * 4]);
        *reinterpret_cast<floatx4*>(&OcB[nb * 16 + u][mb * 16 + qd * 4]) = OT[mb][nb];
      }
  }
  __syncthreads();
  if (w == 0) {
#pragma unroll
    for (int mb = 0; mb < 4; ++mb)
#pragma unroll
      for (int nb = 0; nb < 4; ++nb) {
        OT[mb][nb] += *reinterpret_cast<const floatx4*>(&OcB[nb * 16 + u][mb * 16 + qd * 4]);
        *reinterpret_cast<floatx4*>(&OcA[nb * 16 + u][mb * 16 + qd * 4]) = OT[mb][nb];
      }
  }
  __syncthreads();

  // cooperative normalize + coalesced store
  {
    int qr = tid >> 2;
    int h0 = (tid & 3) * 16;
    float Ltot = (Lc[0][qr] + Lc[1][qr]) + (Lc[2][qr] + Lc[3][qr]);
    float inv = 1.0f / Ltot;
    float* op = out + ((size_t)b * 4096 + g0 + qr) * 64 + h0;
#pragma unroll
    for (int c = 0; c < 4; ++c) {
      floatx4 v = *reinterpret_cast<const floatx4*>(&OcA[qr][h0 + c * 4]);
      v *= inv;
      *reinterpret_cast<floatx4*>(&op[c * 4]) = v;
    }
  }
}

// ---------------------------------------------------------------------------
extern "C" void kernel_launch(void* const* d_in, const int* in_sizes, int n_in,
                              void* d_out, int out_size, void* d_ws, size_t ws_size,
                              hipStream_t stream) {
  const float* x  = (const float*)d_in[0];  // [8][4096][512] fp32
  const float* Wq = (const float*)d_in[1];  // [512][64] fp32
  const float* Wk = (const float*)d_in[2];
  const float* Wv = (const float*)d_in[3];

  unsigned short* ws = (unsigned short*)d_ws;
  unsigned short* Wtf = ws;                  // 98304 shorts (frag-linear weights)
  unsigned short* qb = ws + 131072;          // 32768*64 bf16 row-major
  unsigned short* kf = qb + 2097152;         // frag-linear K tiles
  unsigned short* vf = kf + 2097152;         // frag-linear V^T tiles

  wtrans<<<384, 256, 0, stream>>>(Wq, Wk, Wv, Wtf);
  proj<<<1024, 256, 0, stream>>>(x, Wtf, qb, kf, vf);
  attn<<<512, 256, 0, stream>>>(qb, kf, vf, (float*)d_out);
}

// Round 2
// 167.726 us; speedup vs baseline: 1.4048x; 1.4048x over previous
//
#include <hip/hip_runtime.h>
#include <hip/hip_bf16.h>

// Head attention, B=8, T=4096, C=512, h=64, prefix-causal mask (j <= max(i,1023)).
// Inputs/output fp32; internal q/Kf/Vf bf16 in ws. Round-8: round-6 structure
// restored (round-7's 4-buffer prefetch spilled: WRITE_SIZE 8->265MB). Kept:
// softmax scale folded into q at proj time. New: K-only register prefetch
// (one kt-iter ahead, +32 VGPR, mov-copy ping) and s_setprio(1) around MFMA
// clusters (barrier-free independent waves = the regime where it measured +).

typedef short short8 __attribute__((ext_vector_type(8)));   // 8 bf16 = 4 VGPRs
typedef float floatx4 __attribute__((ext_vector_type(4)));

// fp32 -> bf16 RNE (scalar)
static __device__ __forceinline__ unsigned short f2b(float f) {
  unsigned u = __float_as_uint(f);
  unsigned r = (u + 0x7fffu + ((u >> 16) & 1u)) >> 16;
  return (unsigned short)r;
}

// pack 2 fp32 -> bf16x2 dword (RNE packed convert)
static __device__ __forceinline__ unsigned pkbf(float lo, float hi) {
  __hip_bfloat162 t = __float22bfloat162_rn(make_float2(lo, hi));
  unsigned d;
  __builtin_memcpy(&d, &t, 4);
  return d;
}

union S8U {
  short8 s;
  unsigned u[4];
};

// ---------------------------------------------------------------------------
// Kernel 0: weights -> frag-linear Wtf[(ks*12 + j)*512 + lane*8 + e] bf16.
__global__ __launch_bounds__(256) void wtrans(
    const float* __restrict__ Wq, const float* __restrict__ Wk,
    const float* __restrict__ Wv, unsigned short* __restrict__ Wtf) {
  int o = blockIdx.x * 256 + threadIdx.x;  // 0..98303
  int e = o & 7;
  int ln = (o >> 3) & 63;
  int jg = o >> 9;          // ks*12 + j, 0..191
  int ks = jg / 12;
  int j = jg % 12;
  int m = j >> 2;
  int n = (j & 3) * 16 + (ln & 15);
  int k = ks * 32 + (ln >> 4) * 8 + e;
  const float* W = (m == 0) ? Wq : (m == 1) ? Wk : Wv;
  Wtf[o] = f2b(W[k * 64 + n]);
}

// ---------------------------------------------------------------------------
// Kernel 1: 1024 blocks x 32 rows. Wave pair pr = w>>1 owns rows g0+pr*16..+15;
// parity p = w&1 takes ks = p, p+2, ... (8 iters). No barriers / no LDS in the
// main loop. One LDS combine, then direct register->global epilogue stores.
// q stored pre-scaled by C^-0.5 * log2e (attn's exp2 then needs no multiply).
__global__ __launch_bounds__(256, 3) void proj(
    const float* __restrict__ x, const unsigned short* __restrict__ Wtf,
    unsigned short* __restrict__ q, unsigned short* __restrict__ Kf,
    unsigned short* __restrict__ Vf) {
  __shared__ float Cc[2][12][16][17];  // partial-acc exchange, padded

  const int tid = threadIdx.x;
  const int lane = tid & 63;
  const int w = tid >> 6;
  const int u = lane & 15;
  const int qd = lane >> 4;
  const int pr = w >> 1;   // row-pair: rows g0 + pr*16 .. +15
  const int p = w & 1;     // ks parity
  const int g0 = blockIdx.x * 32;

  floatx4 acc[12];
#pragma unroll
  for (int j = 0; j < 12; ++j) acc[j] = (floatx4)0.0f;

  const float* xr = x + (size_t)(g0 + pr * 16 + u) * 512;

  for (int it = 0; it < 8; ++it) {
    const int ks = p + it * 2;
    floatx4 x0 = *reinterpret_cast<const floatx4*>(&xr[ks * 32 + qd * 8]);
    floatx4 x1 = *reinterpret_cast<const floatx4*>(&xr[ks * 32 + qd * 8 + 4]);
    S8U a;
    a.u[0] = pkbf(x0[0], x0[1]);
    a.u[1] = pkbf(x0[2], x0[3]);
    a.u[2] = pkbf(x1[0], x1[1]);
    a.u[3] = pkbf(x1[2], x1[3]);
#pragma unroll
    for (int j = 0; j < 12; ++j) {
      short8 bfr = *reinterpret_cast<const short8*>(&Wtf[(size_t)(ks * 12 + j) * 512 + lane * 8]);
      acc[j] = __builtin_amdgcn_mfma_f32_16x16x32_bf16(a.s, bfr, acc[j], 0, 0, 0);
    }
  }

  // combine parities: p==1 publishes, p==0 adds
  if (p == 1) {
#pragma unroll
    for (int j = 0; j < 12; ++j)
#pragma unroll
      for (int r = 0; r < 4; ++r)
        Cc[pr][j][qd * 4 + r][u] = acc[j][r];
  }
  __syncthreads();
  if (p == 0) {
#pragma unroll
    for (int j = 0; j < 12; ++j)
#pragma unroll
      for (int r = 0; r < 4; ++r)
        acc[j][r] += Cc[pr][j][qd * 4 + r][u];

    // ---- epilogue (2 active waves, 16 rows each) ----
    const float cexp = 0.04419417382415922f * 1.4426950408889634f;  // C^-0.5*log2e
    const int rbase = g0 + pr * 16;
    const int b = rbase >> 12;
    const int t = rbase & 4095;
    const int kt = t >> 6;
    const int sb = ((blockIdx.x & 1) << 1) + pr;      // K frag row-block in tile
    const int sp = blockIdx.x & 1;                     // V frag s-half in tile
    unsigned short* kfb = Kf + ((size_t)(b * 64 + kt)) * 4096;
    unsigned short* vfb = Vf + ((size_t)(b * 64 + kt)) * 4096;

#pragma unroll
    for (int j = 0; j < 4; ++j)
#pragma unroll
      for (int r = 0; r < 4; ++r) {
        // q row-major, pre-scaled so attn's exp2 needs no multiply
        q[(size_t)(rbase + qd * 4 + r) * 64 + j * 16 + u] = f2b(acc[j][r] * cexp);
        // Kf: frag f = kh*4+sb; lane (qd_f, u_f=qd*4+r), elem e=u&7
        {
          int kh = j >> 1;
          int qd_f = ((j & 1) << 1) + (u >> 3);
          kfb[(size_t)(kh * 4 + sb) * 512 + (qd_f * 16 + (qd * 4 + r)) * 8 + (u & 7)] =
              f2b(acc[4 + j][r]);
        }
        // Vf: frag f = sp*4+mb (mb=j); lane (qd_f, u_f=u), elem e
        {
          int qd_f = pr * 2 + (qd >> 1);
          int e = ((qd & 1) << 2) + r;
          vfb[(size_t)(sp * 4 + j) * 512 + (qd_f * 16 + u) * 8 + e] = f2b(acc[8 + j][r]);
        }
      }
  }
}

// ---------------------------------------------------------------------------
// Kernel 2: flash attention, transposed-S. 512 blocks (b = bx&7 -> XCD, qt
// paired heavy/light). 4 waves each own ALL 64 q-rows for kt = w, w+4, ...
// S^T = K Q^T (A=K frag-linear, B=Q rows); P^T packed in-register to B-frags
// via b64 LDS bounce; O^T = V^T P^T. K frags prefetched one kt-iter ahead
// (single extra 32-VGPR buffer, mov-copied at iter end). s_setprio(1) wraps
// the MFMA clusters. One 3-barrier combine at the end.
__global__ __launch_bounds__(256, 2) void attn(
    const unsigned short* __restrict__ q, const unsigned short* __restrict__ Kf,
    const unsigned short* __restrict__ Vf, float* __restrict__ out) {
  __shared__ unsigned Pb[4][4][64][4];   // [wave][nb][lane][dword] 16 KB
  __shared__ float OcA[64][68];          // combine buffers [qr][h], padded
  __shared__ float OcB[64][68];
  __shared__ float Lc[4][64];

  const int tid = threadIdx.x;
  const int lane = tid & 63;
  const int w = tid >> 6;
  const int u = lane & 15;
  const int qd = lane >> 4;

  const int bx = blockIdx.x;
  const int b = bx & 7;
  const int i = bx >> 3;
  const int qt = (i < 32) ? i : (95 - i);
  const int g0 = qt * 64;

  const unsigned short* qp = q + (size_t)b * 4096 * 64;
  const unsigned short* kfp = Kf + (size_t)b * 64 * 4096;
  const unsigned short* vfp = Vf + (size_t)b * 64 * 4096;

  // Q B-frags (all 64 rows): qB[nb][kh]
  short8 qB[4][2];
#pragma unroll
  for (int nb = 0; nb < 4; ++nb)
#pragma unroll
    for (int kh = 0; kh < 2; ++kh)
      qB[nb][kh] = *reinterpret_cast<const short8*>(
          &qp[(size_t)(g0 + nb * 16 + u) * 64 + kh * 32 + qd * 8]);

  floatx4 OT[4][4];  // [mb][nb]: O^T[h=mb*16+qd*4+r][qr=nb*16+u]
#pragma unroll
  for (int mb = 0; mb < 4; ++mb)
#pragma unroll
    for (int nb = 0; nb < 4; ++nb) OT[mb][nb] = (floatx4)0.0f;
  float L[4] = {0.f, 0.f, 0.f, 0.f};

  const int ktmax = (qt < 16) ? 15 : qt;

  // K frag registers: kA = current tile, kN = next-tile prefetch
  short8 kA[8], kN[8];
  {
    const unsigned short* kb0 = kfp + (size_t)w * 4096;
#pragma unroll
    for (int f = 0; f < 8; ++f)
      kA[f] = *reinterpret_cast<const short8*>(&kb0[(size_t)f * 512 + lane * 8]);
  }

  for (int kt = w; kt <= ktmax; kt += 4) {
    const int ktn = kt + 4;
    const bool havenext = (ktn <= ktmax);
    if (havenext) {
      const unsigned short* kbn = kfp + (size_t)ktn * 4096;
#pragma unroll
      for (int f = 0; f < 8; ++f)
        kN[f] = *reinterpret_cast<const short8*>(&kbn[(size_t)f * 512 + lane * 8]);
    }

    const unsigned short* vb = vfp + (size_t)kt * 4096;
    const bool diag = (qt >= 16) && (kt == qt);

#pragma unroll
    for (int sp = 0; sp < 2; ++sp) {
      short8 vA[4];  // frag f = sp*4+mb
#pragma unroll
      for (int mb = 0; mb < 4; ++mb)
        vA[mb] = *reinterpret_cast<const short8*>(
            &vb[(size_t)(sp * 4 + mb) * 512 + lane * 8]);

      floatx4 ST[2][4];  // [sbb][nb]: S^T[s=(sp*2+sbb)*16+qd*4+r][qr=nb*16+u]
#pragma unroll
      for (int sbb = 0; sbb < 2; ++sbb)
#pragma unroll
        for (int nb = 0; nb < 4; ++nb) ST[sbb][nb] = (floatx4)0.0f;

      __builtin_amdgcn_s_setprio(1);
#pragma unroll
      for (int kh = 0; kh < 2; ++kh)
#pragma unroll
        for (int sbb = 0; sbb < 2; ++sbb)
#pragma unroll
          for (int nb = 0; nb < 4; ++nb)
            ST[sbb][nb] = __builtin_amdgcn_mfma_f32_16x16x32_bf16(
                kA[kh * 4 + sp * 2 + sbb], qB[nb][kh], ST[sbb][nb], 0, 0, 0);
      __builtin_amdgcn_s_setprio(0);

      if (diag) {
#pragma unroll
        for (int sbb = 0; sbb < 2; ++sbb)
#pragma unroll
          for (int nb = 0; nb < 4; ++nb)
#pragma unroll
            for (int r = 0; r < 4; ++r) {
              int sl = (sp * 2 + sbb) * 16 + qd * 4 + r;
              int qr = nb * 16 + u;
              if (sl > qr) ST[sbb][nb][r] = -__builtin_inff();
            }
      }

      // exp + L partials + pack to B-frag dwords in LDS (q pre-scaled in proj)
#pragma unroll
      for (int sbb = 0; sbb < 2; ++sbb)
#pragma unroll
        for (int nb = 0; nb < 4; ++nb) {
#pragma unroll
          for (int r = 0; r < 4; ++r)
            ST[sbb][nb][r] = __builtin_amdgcn_exp2f(ST[sbb][nb][r]);
          L[nb] += (ST[sbb][nb][0] + ST[sbb][nb][1]) + (ST[sbb][nb][2] + ST[sbb][nb][3]);
          unsigned lo = pkbf(ST[sbb][nb][0], ST[sbb][nb][1]);
          unsigned hi = pkbf(ST[sbb][nb][2], ST[sbb][nb][3]);
          int dl = (sbb * 2 + (qd >> 1)) * 16 + u;  // dest lane
          int d0 = (qd & 1) * 2;                    // dest dword pair
          *reinterpret_cast<uint2*>(&Pb[w][nb][dl][d0]) = make_uint2(lo, hi);
        }

      // PV: O^T += V^T P^T
      __builtin_amdgcn_s_setprio(1);
#pragma unroll
      for (int nb = 0; nb < 4; ++nb) {
        short8 pB = *reinterpret_cast<const short8*>(&Pb[w][nb][lane][0]);
#pragma unroll
        for (int mb = 0; mb < 4; ++mb)
          OT[mb][nb] = __builtin_amdgcn_mfma_f32_16x16x32_bf16(vA[mb], pB, OT[mb][nb], 0, 0, 0);
      }
      __builtin_amdgcn_s_setprio(0);
    }

    if (havenext) {
#pragma unroll
      for (int f = 0; f < 8; ++f) kA[f] = kN[f];
    }
  }

  // ---- combine across the 4 kt-split waves ----
#pragma unroll
  for (int nb = 0; nb < 4; ++nb) {
    L[nb] += __shfl_xor(L[nb], 16);
    L[nb] += __shfl_xor(L[nb], 32);
  }
  if (lane < 16) {
#pragma unroll
    for (int nb = 0; nb < 4; ++nb) Lc[w][nb * 16 + lane] = L[nb];
  }

  if (w == 1) {
#pragma unroll
    for (int mb = 0; mb < 4; ++mb)
#pragma unroll
      for (int nb = 0; nb < 4; ++nb)
        *reinterpret_cast<floatx4*>(&OcA[nb * 16 + u][mb * 16 + qd * 4]) = OT[mb][nb];
  }
  if (w == 3) {
#pragma unroll
    for (int mb = 0; mb < 4; ++mb)
#pragma unroll
      for (int nb = 0; nb < 4; ++nb)
        *reinterpret_cast<floatx4*>(&OcB[nb * 16 + u][mb * 16 + qd * 4]) = OT[mb][nb];
  }
  __syncthreads();
  if (w == 0) {
#pragma unroll
    for (int mb = 0; mb < 4; ++mb)
#pragma unroll
      for (int nb = 0; nb < 4; ++nb)
        OT[mb][nb] += *reinterpret_cast<const floatx4*>(&OcA[nb * 16 + u][mb * 16 + qd * 4]);
  }
  if (w == 2) {
#pragma unroll
    for (int mb = 0; mb < 4; ++mb)
#pragma unroll
      for (int nb = 0; nb < 4; ++nb) {
        OT[mb][nb] += *reinterpret_cast<const floatx4*>(&OcB[nb * 16 + u][mb * 16 + qd * 4]);
        *reinterpret_cast<floatx4*>(&OcB[nb * 16 + u][mb * 16 + qd * 4]) = OT[mb][nb];
      }
  }
  __syncthreads();
  if (w == 0) {
#pragma unroll
    for (int mb = 0; mb < 4; ++mb)
#pragma unroll
      for (int nb = 0; nb < 4; ++nb) {
        OT[mb][nb] += *reinterpret_cast<const floatx4*>(&OcB[nb * 16 + u][mb * 16 + qd * 4]);
        *reinterpret_cast<floatx4*>(&OcA[nb * 16 + u][mb * 16 + qd * 4]) = OT[mb][nb];
      }
  }
  __syncthreads();

  // cooperative normalize + coalesced store
  {
    int qr = tid >> 2;
    int h0 = (tid & 3) * 16;
    float Ltot = (Lc[0][qr] + Lc[1][qr]) + (Lc[2][qr] + Lc[3][qr]);
    float inv = 1.0f / Ltot;
    float* op = out + ((size_t)b * 4096 + g0 + qr) * 64 + h0;
#pragma unroll
    for (int c = 0; c < 4; ++c) {
      floatx4 v = *reinterpret_cast<const floatx4*>(&OcA[qr][h0 + c * 4]);
      v *= inv;
      *reinterpret_cast<floatx4*>(&op[c * 4]) = v;
    }
  }
}

// ---------------------------------------------------------------------------
extern "C" void kernel_launch(void* const* d_in, const int* in_sizes, int n_in,
                              void* d_out, int out_size, void* d_ws, size_t ws_size,
                              hipStream_t stream) {
  const float* x  = (const float*)d_in[0];  // [8][4096][512] fp32
  const float* Wq = (const float*)d_in[1];  // [512][64] fp32
  const float* Wk = (const float*)d_in[2];
  const float* Wv = (const float*)d_in[3];

  unsigned short* ws = (unsigned short*)d_ws;
  unsigned short* Wtf = ws;                  // 98304 shorts (frag-linear weights)
  unsigned short* qb = ws + 131072;          // 32768*64 bf16 row-major
  unsigned short* kf = qb + 2097152;         // frag-linear K tiles
  unsigned short* vf = kf + 2097152;         // frag-linear V^T tiles

  wtrans<<<384, 256, 0, stream>>>(Wq, Wk, Wv, Wtf);
  proj<<<1024, 256, 0, stream>>>(x, Wtf, qb, kf, vf);
  attn<<<512, 256, 0, stream>>>(qb, kf, vf, (float*)d_out);
}

// Round 3
// 159.085 us; speedup vs baseline: 1.4811x; 1.0543x over previous
//
#include <hip/hip_runtime.h>
#include <hip/hip_bf16.h>

// Head attention, B=8, T=4096, C=512, h=64, prefix-causal mask (j <= max(i,1023)).
// Inputs/output fp32; internal q/Kf/Vf bf16 in ws. Round-9: attn re-tiled to
// 32 Q-rows/block (grid 1024): halves registers (no spill headroom existed at
// 64 rows -- rounds 7/8 both spilled) and LDS (26 KB), so 4 blocks/CU resident
// = 16 waves/CU (was 8). Latency-bound kernel -> TLP doubling. Keeps cexp fold
// into q, setprio around MFMA, even-j diag half-tile skip. proj/wtrans as
// round-6 (+ cexp fold).

typedef short short8 __attribute__((ext_vector_type(8)));   // 8 bf16 = 4 VGPRs
typedef float floatx4 __attribute__((ext_vector_type(4)));

// fp32 -> bf16 RNE (scalar)
static __device__ __forceinline__ unsigned short f2b(float f) {
  unsigned u = __float_as_uint(f);
  unsigned r = (u + 0x7fffu + ((u >> 16) & 1u)) >> 16;
  return (unsigned short)r;
}

// pack 2 fp32 -> bf16x2 dword (RNE packed convert)
static __device__ __forceinline__ unsigned pkbf(float lo, float hi) {
  __hip_bfloat162 t = __float22bfloat162_rn(make_float2(lo, hi));
  unsigned d;
  __builtin_memcpy(&d, &t, 4);
  return d;
}

union S8U {
  short8 s;
  unsigned u[4];
};

// ---------------------------------------------------------------------------
// Kernel 0: weights -> frag-linear Wtf[(ks*12 + j)*512 + lane*8 + e] bf16.
__global__ __launch_bounds__(256) void wtrans(
    const float* __restrict__ Wq, const float* __restrict__ Wk,
    const float* __restrict__ Wv, unsigned short* __restrict__ Wtf) {
  int o = blockIdx.x * 256 + threadIdx.x;  // 0..98303
  int e = o & 7;
  int ln = (o >> 3) & 63;
  int jg = o >> 9;          // ks*12 + j, 0..191
  int ks = jg / 12;
  int j = jg % 12;
  int m = j >> 2;
  int n = (j & 3) * 16 + (ln & 15);
  int k = ks * 32 + (ln >> 4) * 8 + e;
  const float* W = (m == 0) ? Wq : (m == 1) ? Wk : Wv;
  Wtf[o] = f2b(W[k * 64 + n]);
}

// ---------------------------------------------------------------------------
// Kernel 1: 1024 blocks x 32 rows. Wave pair pr = w>>1 owns rows g0+pr*16..+15;
// parity p = w&1 takes ks = p, p+2, ... (8 iters). No barriers / no LDS in the
// main loop. One LDS combine, then direct register->global epilogue stores.
// q stored pre-scaled by C^-0.5 * log2e (attn's exp2 then needs no multiply).
__global__ __launch_bounds__(256, 3) void proj(
    const float* __restrict__ x, const unsigned short* __restrict__ Wtf,
    unsigned short* __restrict__ q, unsigned short* __restrict__ Kf,
    unsigned short* __restrict__ Vf) {
  __shared__ float Cc[2][12][16][17];  // partial-acc exchange, padded

  const int tid = threadIdx.x;
  const int lane = tid & 63;
  const int w = tid >> 6;
  const int u = lane & 15;
  const int qd = lane >> 4;
  const int pr = w >> 1;   // row-pair: rows g0 + pr*16 .. +15
  const int p = w & 1;     // ks parity
  const int g0 = blockIdx.x * 32;

  floatx4 acc[12];
#pragma unroll
  for (int j = 0; j < 12; ++j) acc[j] = (floatx4)0.0f;

  const float* xr = x + (size_t)(g0 + pr * 16 + u) * 512;

  for (int it = 0; it < 8; ++it) {
    const int ks = p + it * 2;
    floatx4 x0 = *reinterpret_cast<const floatx4*>(&xr[ks * 32 + qd * 8]);
    floatx4 x1 = *reinterpret_cast<const floatx4*>(&xr[ks * 32 + qd * 8 + 4]);
    S8U a;
    a.u[0] = pkbf(x0[0], x0[1]);
    a.u[1] = pkbf(x0[2], x0[3]);
    a.u[2] = pkbf(x1[0], x1[1]);
    a.u[3] = pkbf(x1[2], x1[3]);
#pragma unroll
    for (int j = 0; j < 12; ++j) {
      short8 bfr = *reinterpret_cast<const short8*>(&Wtf[(size_t)(ks * 12 + j) * 512 + lane * 8]);
      acc[j] = __builtin_amdgcn_mfma_f32_16x16x32_bf16(a.s, bfr, acc[j], 0, 0, 0);
    }
  }

  // combine parities: p==1 publishes, p==0 adds
  if (p == 1) {
#pragma unroll
    for (int j = 0; j < 12; ++j)
#pragma unroll
      for (int r = 0; r < 4; ++r)
        Cc[pr][j][qd * 4 + r][u] = acc[j][r];
  }
  __syncthreads();
  if (p == 0) {
#pragma unroll
    for (int j = 0; j < 12; ++j)
#pragma unroll
      for (int r = 0; r < 4; ++r)
        acc[j][r] += Cc[pr][j][qd * 4 + r][u];

    // ---- epilogue (2 active waves, 16 rows each) ----
    const float cexp = 0.04419417382415922f * 1.4426950408889634f;  // C^-0.5*log2e
    const int rbase = g0 + pr * 16;
    const int b = rbase >> 12;
    const int t = rbase & 4095;
    const int kt = t >> 6;
    const int sb = ((blockIdx.x & 1) << 1) + pr;      // K frag row-block in tile
    const int sp = blockIdx.x & 1;                     // V frag s-half in tile
    unsigned short* kfb = Kf + ((size_t)(b * 64 + kt)) * 4096;
    unsigned short* vfb = Vf + ((size_t)(b * 64 + kt)) * 4096;

#pragma unroll
    for (int j = 0; j < 4; ++j)
#pragma unroll
      for (int r = 0; r < 4; ++r) {
        // q row-major, pre-scaled so attn's exp2 needs no multiply
        q[(size_t)(rbase + qd * 4 + r) * 64 + j * 16 + u] = f2b(acc[j][r] * cexp);
        // Kf: frag f = kh*4+sb; lane (qd_f, u_f=qd*4+r), elem e=u&7
        {
          int kh = j >> 1;
          int qd_f = ((j & 1) << 1) + (u >> 3);
          kfb[(size_t)(kh * 4 + sb) * 512 + (qd_f * 16 + (qd * 4 + r)) * 8 + (u & 7)] =
              f2b(acc[4 + j][r]);
        }
        // Vf: frag f = sp*4+mb (mb=j); lane (qd_f, u_f=u), elem e
        {
          int qd_f = pr * 2 + (qd >> 1);
          int e = ((qd & 1) << 2) + r;
          vfb[(size_t)(sp * 4 + j) * 512 + (qd_f * 16 + u) * 8 + e] = f2b(acc[8 + j][r]);
        }
      }
  }
}

// ---------------------------------------------------------------------------
// Kernel 2: flash attention, transposed-S, 32 Q-rows per block. 1024 blocks
// (b = bx&7 -> XCD; i=bx>>3 alternates light/heavy j). 4 waves each own ALL
// 32 q-rows for kt = w, w+4, ... S^T = K Q^T; P^T packed in-register to
// B-frags via b64 LDS bounce; O^T = V^T P^T. One 3-barrier combine at end.
__global__ __launch_bounds__(256, 4) void attn(
    const unsigned short* __restrict__ q, const unsigned short* __restrict__ Kf,
    const unsigned short* __restrict__ Vf, float* __restrict__ out) {
  __shared__ unsigned Pb[4][2][64][4];   // [wave][nb][lane][dword] 8 KB
  __shared__ float OcA[32][68];          // combine buffers [qr][h], padded
  __shared__ float OcB[32][68];
  __shared__ float Lc[4][32];

  const int tid = threadIdx.x;
  const int lane = tid & 63;
  const int w = tid >> 6;
  const int u = lane & 15;
  const int qd = lane >> 4;

  const int bx = blockIdx.x;
  const int b = bx & 7;
  const int i = bx >> 3;                       // 0..127
  const int j = (i & 1) ? (127 - (i >> 1)) : (i >> 1);  // qt32, light/heavy paired
  const int g0 = j * 32;

  const unsigned short* qp = q + (size_t)b * 4096 * 64;
  const unsigned short* kfp = Kf + (size_t)b * 64 * 4096;
  const unsigned short* vfp = Vf + (size_t)b * 64 * 4096;

  // Q B-frags (32 rows): qB[nb][kh]
  short8 qB[2][2];
#pragma unroll
  for (int nb = 0; nb < 2; ++nb)
#pragma unroll
    for (int kh = 0; kh < 2; ++kh)
      qB[nb][kh] = *reinterpret_cast<const short8*>(
          &qp[(size_t)(g0 + nb * 16 + u) * 64 + kh * 32 + qd * 8]);

  floatx4 OT[4][2];  // [mb][nb]: O^T[h=mb*16+qd*4+r][qr=nb*16+u]
#pragma unroll
  for (int mb = 0; mb < 4; ++mb)
#pragma unroll
    for (int nb = 0; nb < 2; ++nb) OT[mb][nb] = (floatx4)0.0f;
  float L[2] = {0.f, 0.f};

  const int kt_half = j >> 1;
  const int ktmax = (kt_half < 15) ? 15 : kt_half;
  const int diagkt = (j >= 32) ? kt_half : -1;   // tile containing the diagonal
  const int doff = (j & 1) << 5;                 // local row offset of diag

  for (int kt = w; kt <= ktmax; kt += 4) {
    const unsigned short* kb = kfp + (size_t)kt * 4096;
    const unsigned short* vb = vfp + (size_t)kt * 4096;
    short8 kA[8];  // frag f = kh*4+sb
#pragma unroll
    for (int f = 0; f < 8; ++f)
      kA[f] = *reinterpret_cast<const short8*>(&kb[(size_t)f * 512 + lane * 8]);
    const bool diag = (kt == diagkt);

#pragma unroll
    for (int sp = 0; sp < 2; ++sp) {
      // even-j diagonal tile: s-half sp=1 is entirely masked -> skip
      if (diag && doff == 0 && sp == 1) continue;

      short8 vA[4];  // frag f = sp*4+mb
#pragma unroll
      for (int mb = 0; mb < 4; ++mb)
        vA[mb] = *reinterpret_cast<const short8*>(
            &vb[(size_t)(sp * 4 + mb) * 512 + lane * 8]);

      floatx4 ST[2][2];  // [sbb][nb]: S^T[s=(sp*2+sbb)*16+qd*4+r][qr=nb*16+u]
#pragma unroll
      for (int sbb = 0; sbb < 2; ++sbb)
#pragma unroll
        for (int nb = 0; nb < 2; ++nb) ST[sbb][nb] = (floatx4)0.0f;

      __builtin_amdgcn_s_setprio(1);
#pragma unroll
      for (int kh = 0; kh < 2; ++kh)
#pragma unroll
        for (int sbb = 0; sbb < 2; ++sbb)
#pragma unroll
          for (int nb = 0; nb < 2; ++nb)
            ST[sbb][nb] = __builtin_amdgcn_mfma_f32_16x16x32_bf16(
                kA[kh * 4 + sp * 2 + sbb], qB[nb][kh], ST[sbb][nb], 0, 0, 0);
      __builtin_amdgcn_s_setprio(0);

      if (diag) {
#pragma unroll
        for (int sbb = 0; sbb < 2; ++sbb)
#pragma unroll
          for (int nb = 0; nb < 2; ++nb)
#pragma unroll
            for (int r = 0; r < 4; ++r) {
              int sl = (sp * 2 + sbb) * 16 + qd * 4 + r;
              int qrl = nb * 16 + u;
              if (sl > qrl + doff) ST[sbb][nb][r] = -__builtin_inff();
            }
      }

      // exp + L partials + pack to B-frag dwords in LDS (q pre-scaled in proj)
#pragma unroll
      for (int sbb = 0; sbb < 2; ++sbb)
#pragma unroll
        for (int nb = 0; nb < 2; ++nb) {
#pragma unroll
          for (int r = 0; r < 4; ++r)
            ST[sbb][nb][r] = __builtin_amdgcn_exp2f(ST[sbb][nb][r]);
          L[nb] += (ST[sbb][nb][0] + ST[sbb][nb][1]) + (ST[sbb][nb][2] + ST[sbb][nb][3]);
          unsigned lo = pkbf(ST[sbb][nb][0], ST[sbb][nb][1]);
          unsigned hi = pkbf(ST[sbb][nb][2], ST[sbb][nb][3]);
          int dl = (sbb * 2 + (qd >> 1)) * 16 + u;  // dest lane
          int d0 = (qd & 1) * 2;                    // dest dword pair
          *reinterpret_cast<uint2*>(&Pb[w][nb][dl][d0]) = make_uint2(lo, hi);
        }

      // PV: O^T += V^T P^T
      __builtin_amdgcn_s_setprio(1);
#pragma unroll
      for (int nb = 0; nb < 2; ++nb) {
        short8 pB = *reinterpret_cast<const short8*>(&Pb[w][nb][lane][0]);
#pragma unroll
        for (int mb = 0; mb < 4; ++mb)
          OT[mb][nb] = __builtin_amdgcn_mfma_f32_16x16x32_bf16(vA[mb], pB, OT[mb][nb], 0, 0, 0);
      }
      __builtin_amdgcn_s_setprio(0);
    }
  }

  // ---- combine across the 4 kt-split waves ----
#pragma unroll
  for (int nb = 0; nb < 2; ++nb) {
    L[nb] += __shfl_xor(L[nb], 16);
    L[nb] += __shfl_xor(L[nb], 32);
  }
  if (lane < 16) {
#pragma unroll
    for (int nb = 0; nb < 2; ++nb) Lc[w][nb * 16 + lane] = L[nb];
  }

  if (w == 1) {
#pragma unroll
    for (int mb = 0; mb < 4; ++mb)
#pragma unroll
      for (int nb = 0; nb < 2; ++nb)
        *reinterpret_cast<floatx4*>(&OcA[nb * 16 + u][mb * 16 + qd * 4]) = OT[mb][nb];
  }
  if (w == 3) {
#pragma unroll
    for (int mb = 0; mb < 4; ++mb)
#pragma unroll
      for (int nb = 0; nb < 2; ++nb)
        *reinterpret_cast<floatx4*>(&OcB[nb * 16 + u][mb * 16 + qd * 4]) = OT[mb][nb];
  }
  __syncthreads();
  if (w == 0) {
#pragma unroll
    for (int mb = 0; mb < 4; ++mb)
#pragma unroll
      for (int nb = 0; nb < 2; ++nb)
        OT[mb][nb] += *reinterpret_cast<const floatx4*>(&OcA[nb * 16 + u][mb * 16 + qd * 4]);
  }
  if (w == 2) {
#pragma unroll
    for (int mb = 0; mb < 4; ++mb)
#pragma unroll
      for (int nb = 0; nb < 2; ++nb) {
        OT[mb][nb] += *reinterpret_cast<const floatx4*>(&OcB[nb * 16 + u][mb * 16 + qd * 4]);
        *reinterpret_cast<floatx4*>(&OcB[nb * 16 + u][mb * 16 + qd * 4]) = OT[mb][nb];
      }
  }
  __syncthreads();
  if (w == 0) {
#pragma unroll
    for (int mb = 0; mb < 4; ++mb)
#pragma unroll
      for (int nb = 0; nb < 2; ++nb) {
        OT[mb][nb] += *reinterpret_cast<const floatx4*>(&OcB[nb * 16 + u][mb * 16 + qd * 4]);
        *reinterpret_cast<floatx4*>(&OcA[nb * 16 + u][mb * 16 + qd * 4]) = OT[mb][nb];
      }
  }
  __syncthreads();

  // cooperative normalize + coalesced store (32 rows x 64 cols)
  {
    int qr = tid >> 3;            // 0..31
    int h0 = (tid & 7) * 8;       // 0..56
    float Ltot = (Lc[0][qr] + Lc[1][qr]) + (Lc[2][qr] + Lc[3][qr]);
    float inv = 1.0f / Ltot;
    float* op = out + ((size_t)b * 4096 + g0 + qr) * 64 + h0;
#pragma unroll
    for (int c = 0; c < 2; ++c) {
      floatx4 v = *reinterpret_cast<const floatx4*>(&OcA[qr][h0 + c * 4]);
      v *= inv;
      *reinterpret_cast<floatx4*>(&op[c * 4]) = v;
    }
  }
}

// ---------------------------------------------------------------------------
extern "C" void kernel_launch(void* const* d_in, const int* in_sizes, int n_in,
                              void* d_out, int out_size, void* d_ws, size_t ws_size,
                              hipStream_t stream) {
  const float* x  = (const float*)d_in[0];  // [8][4096][512] fp32
  const float* Wq = (const float*)d_in[1];  // [512][64] fp32
  const float* Wk = (const float*)d_in[2];
  const float* Wv = (const float*)d_in[3];

  unsigned short* ws = (unsigned short*)d_ws;
  unsigned short* Wtf = ws;                  // 98304 shorts (frag-linear weights)
  unsigned short* qb = ws + 131072;          // 32768*64 bf16 row-major
  unsigned short* kf = qb + 2097152;         // frag-linear K tiles
  unsigned short* vf = kf + 2097152;         // frag-linear V^T tiles

  wtrans<<<384, 256, 0, stream>>>(Wq, Wk, Wv, Wtf);
  proj<<<1024, 256, 0, stream>>>(x, Wtf, qb, kf, vf);
  attn<<<1024, 256, 0, stream>>>(qb, kf, vf, (float*)d_out);
}